// Round 17
// baseline (601.651 us; speedup 1.0000x reference)
//
#include <hip/hip_runtime.h>
#include <hip/hip_fp16.h>
#include <math.h>

#define N_NODES 100000
#define N_EDGES 600000
#define NB_SCAN ((N_NODES + 1023) / 1024)   // 98 scan blocks of 1024
#define EGRID   ((N_EDGES + 255) / 256)     // 2344 edge-grid blocks
#define NZGRID  ((N_NODES * 32 + 255) / 256) // 12500 npre blocks

typedef unsigned short u16;
typedef __bf16 bf16x8 __attribute__((ext_vector_type(8)));
typedef float  f32x4  __attribute__((ext_vector_type(4)));

__device__ __forceinline__ u16 f2bf(float f) {
    union { float f; unsigned u; } c; c.f = f;
    unsigned u = c.u + 0x7fffu + ((c.u >> 16) & 1u);   // RNE
    return (u16)(u >> 16);
}
__device__ __forceinline__ float bf2f(u16 h) {
    union { unsigned u; float f; } c; c.u = ((unsigned)h) << 16;
    return c.f;
}
// fast tanh: tanh(x) = 1 - 2/(exp(2x)+1); saturates correctly at +-inf.
__device__ __forceinline__ float fast_tanh(float x) {
    float e = __expf(2.0f * x);                 // v_exp_f32 path
    return 1.0f - 2.0f * __builtin_amdgcn_rcpf(e + 1.0f);
}

// ===========================================================================
// CSR build: counting sort of edges by dst (once per launch).
// hist fused with weight prep (independent work, disjoint block ranges).
// ===========================================================================
__global__ void hist_wprep_k(const int* __restrict__ dst, int* __restrict__ counts,
                             int* __restrict__ rank,
                             const float* __restrict__ W1a, const float* __restrict__ W1b,
                             const float* __restrict__ W2a, const float* __restrict__ W2b,
                             const float* __restrict__ Wf1, const float* __restrict__ Wf2,
                             const float* __restrict__ We1, const float* __restrict__ We2,
                             u16* __restrict__ wT)
{
    if (blockIdx.x < EGRID) {               // ---- hist part ----
        int e = blockIdx.x * 256 + threadIdx.x;
        if (e < N_EDGES) rank[e] = atomicAdd(&counts[dst[e]], 1);
        return;
    }
    // ---- weight-prep part ----
    int idx = (blockIdx.x - EGRID) * 256 + threadIdx.x;
    if (idx >= 98304) return;
    if (idx >= 90112) {                    // edge-linear WeT blocks
        int l = idx - 90112;               // 0..8191
        const int m = l >> 12;             // 0: We1, 1: We2
        l &= 4095;
        const float* src = m ? We2 : We1;
        const int k = l >> 7, n = l & 127; // We is [32][128]
        const float w = src[k * 128 + n];
        const u16 hi = f2bf(w);
        const u16 lo = f2bf(w - bf2f(hi));
        const int base = 180224 + m * 8192;
        wT[base + n * 32 + k]        = hi;
        wT[base + 4096 + n * 32 + k] = lo;
        return;
    }
    int m, local;
    if      (idx < 16384) { m = 0; local = idx; }
    else if (idx < 32768) { m = 1; local = idx - 16384; }
    else if (idx < 49152) { m = 2; local = idx - 32768; }
    else if (idx < 65536) { m = 3; local = idx - 49152; }
    else if (idx < 81920) { m = 4; local = idx - 65536; }
    else                  { m = 5; local = idx - 81920; }
    const int N = (m == 5) ? 64 : 128;
    const float* src = (m == 0) ? W1a : (m == 1) ? W1b : (m == 2) ? W2a
                     : (m == 3) ? W2b : (m == 4) ? Wf1 : Wf2;
    const int k = local / N, n = local % N;
    const float w = src[k * N + n];
    const u16 hi = f2bf(w);
    const u16 lo = f2bf(w - bf2f(hi));
    const int base = m * 32768;
    const int sz   = (m == 5) ? 8192 : 16384;
    wT[base + n * 128 + k]      = hi;
    wT[base + sz + n * 128 + k] = lo;
}

__global__ void scan_a_k(const int* __restrict__ counts, int* __restrict__ row_ptr,
                         int* __restrict__ blockSums)
{
    __shared__ int s[256];
    const int t = threadIdx.x;
    const int base = blockIdx.x * 1024 + t * 4;
    int c[4];
#pragma unroll
    for (int j = 0; j < 4; ++j) c[j] = (base + j < N_NODES) ? counts[base + j] : 0;
    const int tot = c[0] + c[1] + c[2] + c[3];
    s[t] = tot;
    __syncthreads();
    for (int off = 1; off < 256; off <<= 1) {
        int v = (t >= off) ? s[t - off] : 0;
        __syncthreads();
        s[t] += v;
        __syncthreads();
    }
    int run = s[t] - tot;
#pragma unroll
    for (int j = 0; j < 4; ++j) {
        if (base + j < N_NODES) row_ptr[base + j] = run;
        run += c[j];
    }
    if (t == 255) blockSums[blockIdx.x] = s[255];
}

// Parallel 128-wide Hillis-Steele scan over the 98 block sums.
__global__ void scan_b_k(const int* __restrict__ blockSums, int* __restrict__ blockOffs)
{
    __shared__ int s[128];
    const int t = threadIdx.x;
    const int v = (t < NB_SCAN) ? blockSums[t] : 0;
    s[t] = v;
    __syncthreads();
    for (int off = 1; off < 128; off <<= 1) {
        const int u = (t >= off) ? s[t - off] : 0;
        __syncthreads();
        s[t] += u;
        __syncthreads();
    }
    if (t < NB_SCAN) blockOffs[t] = s[t] - v;   // exclusive prefix
}

__global__ void scan_c_k(int* __restrict__ row_ptr, const int* __restrict__ blockOffs)
{
    int i = blockIdx.x * 256 + threadIdx.x;
    if (i < N_NODES) row_ptr[i] += blockOffs[i >> 10];
    if (i == 0) row_ptr[N_NODES] = N_EDGES;
}

// Scatter (edge sort) fused with npre (agg[n]=x[n] preload for non-interior
// rows). Both depend only on scan_c; disjoint block ranges.
__global__ void scatter_npre_k(const int* __restrict__ src, const int* __restrict__ dst,
                               const int* __restrict__ row_ptr, const int* __restrict__ rank,
                               int* __restrict__ perm, int* __restrict__ src_sorted,
                               int* __restrict__ dst_sorted,
                               const float* __restrict__ xin, float* __restrict__ agg)
{
    if (blockIdx.x < EGRID) {               // ---- scatter part ----
        int e = blockIdx.x * 256 + threadIdx.x;
        if (e < N_EDGES) {
            int pos = row_ptr[dst[e]] + rank[e];
            perm[pos] = e;
            src_sorted[pos] = src[e];
            dst_sorted[pos] = dst[e];
        }
        return;
    }
    // ---- npre part: 32 threads per node, one float4 each ----
    const int idx = (blockIdx.x - EGRID) * 256 + threadIdx.x;
    const int n = idx >> 5;
    if (n >= N_NODES) return;
    const int rs = row_ptr[n], re = row_ptr[n + 1];
    const bool interior = (rs < re) && ((rs >> 6) == ((re - 1) >> 6));
    if (!interior) {
        const int c = (idx & 31) * 4;
        *(float4*)(agg + (size_t)n * 128 + c) =
            *(const float4*)(xin + (size_t)n * 128 + c);
    }
}

// ===========================================================================
// FUSED conv kernel — round-12 proven body + round-15 nt ef loads.
// Round-17: (256,6) -> (256,8). VGPR_Count measured 40 < the 64-VGPR cap
// at 8 waves/EU (round-5/10 spilled because their live sets were ~80);
// LDS 17.4 KB x 8 blocks = 139 KB < 160 KB. Occupancy cap 75% -> 100%.
// Tripwire: WRITE_SIZE must stay 61.7 MB (spill detector).
// ===========================================================================
__global__ __launch_bounds__(256, 8) void fused_conv_k(
    const float* __restrict__ x, const float* __restrict__ ef,
    const int* __restrict__ perm, const int* __restrict__ src_s,
    const int* __restrict__ dst_s, const int* __restrict__ row_ptr,
    const u16* __restrict__ WeT_hi, const u16* __restrict__ WeT_lo,
    const float* __restrict__ be, float* __restrict__ agg)
{
    __shared__ __align__(16) char smem[16896];      // union: ef hi/lo | msg16
    u16 (*efHi)[40]  = (u16 (*)[40])smem;                    // 5120 B
    u16 (*efLo)[40]  = (u16 (*)[40])(smem + 5120);           // 5120 B
    u16 (*msg16)[132] = (u16 (*)[132])smem;                  // 16896 B overlay
    __shared__ int sSrc[64];
    __shared__ int sDst[64];

    const int t  = threadIdx.x;
    const int i0 = blockIdx.x * 64;

    // ---- stage: ef rows -> bf16 hi/lo tile; edge ids ----
    if (t < 64) { sSrc[t] = src_s[i0 + t]; sDst[t] = dst_s[i0 + t]; }
    {
        const int row = t >> 2;
        const int q   = t & 3;                      // k-range q*8 .. q*8+7
        const int e   = perm[i0 + row];
        const f32x4* p = (const f32x4*)(ef + (size_t)e * 32 + q * 8);
        const f32x4 v0 = __builtin_nontemporal_load(p);       // read-once stream
        const f32x4 v1 = __builtin_nontemporal_load(p + 1);   // -> nt hint
        const float vv[8] = {v0.x, v0.y, v0.z, v0.w, v1.x, v1.y, v1.z, v1.w};
        unsigned hp[4], lp[4];
#pragma unroll
        for (int i = 0; i < 4; ++i) {
            const u16 h0 = f2bf(vv[2 * i]),     h1 = f2bf(vv[2 * i + 1]);
            const u16 l0 = f2bf(vv[2 * i]     - bf2f(h0));
            const u16 l1 = f2bf(vv[2 * i + 1] - bf2f(h1));
            hp[i] = (unsigned)h0 | ((unsigned)h1 << 16);
            lp[i] = (unsigned)l0 | ((unsigned)l1 << 16);
        }
        *(uint4*)&efHi[row][q * 8] = make_uint4(hp[0], hp[1], hp[2], hp[3]);
        *(uint4*)&efLo[row][q * 8] = make_uint4(lp[0], lp[1], lp[2], lp[3]);
    }
    __syncthreads();

    const int lane = t & 63, wave = t >> 6;
    const int quad = lane >> 4, col = lane & 15;

    // ---- B fragments (WeT, L2-hot) for this wave's 2 col-tiles ----
    bf16x8 bHi[2], bLo[2];
#pragma unroll
    for (int j = 0; j < 2; ++j) {
        const int nt = wave * 2 + j;
        const size_t off = (size_t)(nt * 16 + col) * 32 + quad * 8;
        bHi[j] = *(const bf16x8*)(WeT_hi + off);
        bLo[j] = *(const bf16x8*)(WeT_lo + off);
    }

    // ---- x gather (32 independent dwords; latency hides under MFMA) ----
    float xv[2][4][4];
#pragma unroll
    for (int m = 0; m < 4; ++m)
#pragma unroll
        for (int r = 0; r < 4; ++r) {
            const int s = sSrc[m * 16 + quad * 4 + r];
            const float* xp = x + (size_t)s * 128 + wave * 32 + col;
            xv[0][m][r] = xp[0];
            xv[1][m][r] = xp[16];
        }

    // ---- MFMA: e = ef @ We + be (3-term hi/lo) ----
    f32x4 acc[2][4];
#pragma unroll
    for (int j = 0; j < 2; ++j) {
        const float bv = be[wave * 32 + j * 16 + col];
#pragma unroll
        for (int m = 0; m < 4; ++m) acc[j][m] = (f32x4){bv, bv, bv, bv};
    }
#pragma unroll
    for (int m = 0; m < 4; ++m) {
        const bf16x8 aHi = *(const bf16x8*)&efHi[m * 16 + col][quad * 8];
        const bf16x8 aLo = *(const bf16x8*)&efLo[m * 16 + col][quad * 8];
#pragma unroll
        for (int j = 0; j < 2; ++j) {
            acc[j][m] = __builtin_amdgcn_mfma_f32_16x16x32_bf16(aHi, bHi[j], acc[j][m], 0, 0, 0);
            acc[j][m] = __builtin_amdgcn_mfma_f32_16x16x32_bf16(aHi, bLo[j], acc[j][m], 0, 0, 0);
            acc[j][m] = __builtin_amdgcn_mfma_f32_16x16x32_bf16(aLo, bHi[j], acc[j][m], 0, 0, 0);
        }
    }

    // ---- msg = relu(x + e) in regs ----
#pragma unroll
    for (int j = 0; j < 2; ++j)
#pragma unroll
        for (int m = 0; m < 4; ++m)
#pragma unroll
            for (int r = 0; r < 4; ++r)
                acc[j][m][r] = fmaxf(acc[j][m][r] + xv[j][m][r], 0.f);

    __syncthreads();            // all ef-tile reads done -> overlay as msg16
#pragma unroll
    for (int j = 0; j < 2; ++j)
#pragma unroll
        for (int m = 0; m < 4; ++m)
#pragma unroll
            for (int r = 0; r < 4; ++r) {
                const __half hv = __float2half_rn(acc[j][m][r]);
                msg16[m * 16 + quad * 4 + r][wave * 32 + j * 16 + col] =
                    *(const u16*)&hv;
            }
    __syncthreads();

    // ---- phase 2: per-node segment sum (fp32 acc) + store/atomic ----
    const int c2 = lane * 2;
    const int nF = sDst[0], nL = sDst[63];
    for (int n = nF + wave; n <= nL; n += 4) {
        const int rs = row_ptr[n];
        const int re = row_ptr[n + 1];
        const float2 xn = *(const float2*)(x + (size_t)n * 128 + c2);  // dst row
        const int lo = rs > i0 ? rs : i0;
        const int hi = re < i0 + 64 ? re : i0 + 64;
        float a0 = 0.f, a1 = 0.f;
        for (int i = lo; i < hi; ++i) {
            const __half2 v = *(const __half2*)(&msg16[i - i0][c2]);
            const float2 f = __half22float2(v);
            a0 += f.x; a1 += f.y;
        }
        float* dp = agg + (size_t)n * 128 + c2;
        const bool interior = (rs >= i0) && (re <= i0 + 64);
        if (interior) {
            *(float2*)dp = make_float2(xn.x + a0, xn.y + a1);
        } else if (hi > lo) {
            atomicAdd(dp,     a0);
            atomicAdd(dp + 1, a1);
        }
    }
}

// ===========================================================================
// Fused 2-layer node MLP (conv1), round-12 proven: 64-row tile, 512 thr /
// 8 waves, ONE col-tile per wave, (512,4). Also seeds agg for conv2's
// non-interior rows (npre fold).
// ===========================================================================
__global__ __launch_bounds__(512, 4) void mlp2_mfma_k(
    const float* __restrict__ agg_in, const int* __restrict__ row_ptr,
    const u16* __restrict__ WaT_hi, const u16* __restrict__ WaT_lo,
    const float* __restrict__ ba,
    const u16* __restrict__ WbT_hi, const u16* __restrict__ WbT_lo,
    const float* __restrict__ bb,
    float* __restrict__ h_out, float* __restrict__ agg_out)
{
    __shared__ u16 sHi[64][136];
    __shared__ u16 sLo[64][136];
    __shared__ int sFlag[64];          // 1 = interior (skip agg preload write)
    const int tid = threadIdx.x;
    const int n0  = blockIdx.x * 64;

    // ---- stage tile: fp32 agg -> bf16 hi/lo in LDS; interior flags ----
    if (tid < 64) {
        int flag = 1;
        const int node = n0 + tid;
        if (node < N_NODES) {
            const int rs = row_ptr[node], re = row_ptr[node + 1];
            flag = (rs < re) && ((rs >> 6) == ((re - 1) >> 6));
        }
        sFlag[tid] = flag;
    }
    {
        const int mrow = tid >> 5, kq = tid & 31;   // mrow 0..15
#pragma unroll
        for (int g = 0; g < 4; ++g) {
            const int row  = g * 16 + mrow;
            const int node = n0 + row;
            float4 v = make_float4(0.f, 0.f, 0.f, 0.f);
            if (node < N_NODES)
                v = *(const float4*)(agg_in + (size_t)node * 128 + kq * 4);
            const u16 h0 = f2bf(v.x), h1 = f2bf(v.y), h2 = f2bf(v.z), h3 = f2bf(v.w);
            const u16 l0 = f2bf(v.x - bf2f(h0)), l1 = f2bf(v.y - bf2f(h1));
            const u16 l2 = f2bf(v.z - bf2f(h2)), l3 = f2bf(v.w - bf2f(h3));
            *(uint2*)&sHi[row][kq * 4] =
                make_uint2((unsigned)h0 | ((unsigned)h1 << 16), (unsigned)h2 | ((unsigned)h3 << 16));
            *(uint2*)&sLo[row][kq * 4] =
                make_uint2((unsigned)l0 | ((unsigned)l1 << 16), (unsigned)l2 | ((unsigned)l3 << 16));
        }
    }
    __syncthreads();

    const int lane = tid & 63, wave = tid >> 6;     // wave = col-tile 0..7
    const int quad = lane >> 4, col = lane & 15;
    const int nt = wave;

    // ---- layer A: this wave's col-tile across all 64 rows ----
    f32x4 accA[4];
    {
        const float bv = ba[nt * 16 + col];
#pragma unroll
        for (int m = 0; m < 4; ++m) accA[m] = (f32x4){bv, bv, bv, bv};
    }
    {
        bf16x8 bHi[4], bLo[4];
#pragma unroll
        for (int k0 = 0; k0 < 4; ++k0) {
            const size_t off = (size_t)(nt * 16 + col) * 128 + k0 * 32 + quad * 8;
            bHi[k0] = *(const bf16x8*)(WaT_hi + off);
            bLo[k0] = *(const bf16x8*)(WaT_lo + off);
        }
#pragma unroll
        for (int m = 0; m < 4; ++m) {
#pragma unroll
            for (int k0 = 0; k0 < 4; ++k0) {
                const bf16x8 aHi = *(const bf16x8*)&sHi[m * 16 + col][k0 * 32 + quad * 8];
                const bf16x8 aLo = *(const bf16x8*)&sLo[m * 16 + col][k0 * 32 + quad * 8];
                accA[m] = __builtin_amdgcn_mfma_f32_16x16x32_bf16(aHi, bHi[k0], accA[m], 0, 0, 0);
                accA[m] = __builtin_amdgcn_mfma_f32_16x16x32_bf16(aHi, bLo[k0], accA[m], 0, 0, 0);
                accA[m] = __builtin_amdgcn_mfma_f32_16x16x32_bf16(aLo, bHi[k0], accA[m], 0, 0, 0);
            }
        }
    }
    __syncthreads();   // all waves done READING the input tile

    // ---- relu + re-split t into the same LDS buffer ----
    {
        const int ct = nt * 16 + col;
#pragma unroll
        for (int m = 0; m < 4; ++m) {
#pragma unroll
            for (int r = 0; r < 4; ++r) {
                float v = fmaxf(accA[m][r], 0.f);
                const u16 hv = f2bf(v);
                const u16 lv = f2bf(v - bf2f(hv));
                const int row = m * 16 + quad * 4 + r;
                sHi[row][ct] = hv;
                sLo[row][ct] = lv;
            }
        }
    }
    __syncthreads();   // t tile fully written

    // ---- layer B: out = tanh(t @ Wb + bb); also seed agg for conv2 ----
    {
        const float bv = bb[nt * 16 + col];
        f32x4 accB[4];
#pragma unroll
        for (int m = 0; m < 4; ++m) accB[m] = (f32x4){bv, bv, bv, bv};

        bf16x8 bHi[4], bLo[4];
#pragma unroll
        for (int k0 = 0; k0 < 4; ++k0) {
            const size_t off = (size_t)(nt * 16 + col) * 128 + k0 * 32 + quad * 8;
            bHi[k0] = *(const bf16x8*)(WbT_hi + off);
            bLo[k0] = *(const bf16x8*)(WbT_lo + off);
        }
#pragma unroll
        for (int m = 0; m < 4; ++m) {
#pragma unroll
            for (int k0 = 0; k0 < 4; ++k0) {
                const bf16x8 tHi = *(const bf16x8*)&sHi[m * 16 + col][k0 * 32 + quad * 8];
                const bf16x8 tLo = *(const bf16x8*)&sLo[m * 16 + col][k0 * 32 + quad * 8];
                accB[m] = __builtin_amdgcn_mfma_f32_16x16x32_bf16(tHi, bHi[k0], accB[m], 0, 0, 0);
                accB[m] = __builtin_amdgcn_mfma_f32_16x16x32_bf16(tHi, bLo[k0], accB[m], 0, 0, 0);
                accB[m] = __builtin_amdgcn_mfma_f32_16x16x32_bf16(tLo, bHi[k0], accB[m], 0, 0, 0);
            }
        }
#pragma unroll
        for (int m = 0; m < 4; ++m) {
#pragma unroll
            for (int r = 0; r < 4; ++r) {
                const int row  = m * 16 + quad * 4 + r;
                const int node = n0 + row;
                if (node < N_NODES) {
                    const float v = fast_tanh(accB[m][r]);
                    const size_t o = (size_t)node * 128 + nt * 16 + col;
                    h_out[o] = v;
                    if (!sFlag[row]) agg_out[o] = v;   // conv2 npre fold
                }
            }
        }
    }
}

// ===========================================================================
// Fused 4-layer tail (conv2 MLP + head), round-12 proven: 64-row tile,
// 512 thr / 8 waves, one col-tile per wave; final layer uses waves 0..3.
// out store is NON-TEMPORAL (never re-read; keeps h/agg cache-resident).
// ===========================================================================
__global__ __launch_bounds__(512, 4) void mlp4_mfma_k(
    const float* __restrict__ agg,
    const u16* __restrict__ W0hi, const u16* __restrict__ W0lo, const float* __restrict__ b0,
    const u16* __restrict__ W1hi, const u16* __restrict__ W1lo, const float* __restrict__ b1,
    const u16* __restrict__ W2hi, const u16* __restrict__ W2lo, const float* __restrict__ b2,
    const u16* __restrict__ W3hi, const u16* __restrict__ W3lo, const float* __restrict__ b3,
    float* __restrict__ out)
{
    __shared__ u16 sHi[64][136];
    __shared__ u16 sLo[64][136];
    const int tid = threadIdx.x;
    const int n0  = blockIdx.x * 64;

    // ---- stage tile: fp32 agg -> bf16 hi/lo in LDS ----
    {
        const int mrow = tid >> 5, kq = tid & 31;   // mrow 0..15
#pragma unroll
        for (int g = 0; g < 4; ++g) {
            const int row  = g * 16 + mrow;
            const int node = n0 + row;
            float4 v = make_float4(0.f, 0.f, 0.f, 0.f);
            if (node < N_NODES)
                v = *(const float4*)(agg + (size_t)node * 128 + kq * 4);
            const u16 h0 = f2bf(v.x), h1 = f2bf(v.y), h2 = f2bf(v.z), h3 = f2bf(v.w);
            const u16 l0 = f2bf(v.x - bf2f(h0)), l1 = f2bf(v.y - bf2f(h1));
            const u16 l2 = f2bf(v.z - bf2f(h2)), l3 = f2bf(v.w - bf2f(h3));
            *(uint2*)&sHi[row][kq * 4] =
                make_uint2((unsigned)h0 | ((unsigned)h1 << 16), (unsigned)h2 | ((unsigned)h3 << 16));
            *(uint2*)&sLo[row][kq * 4] =
                make_uint2((unsigned)l0 | ((unsigned)l1 << 16), (unsigned)l2 | ((unsigned)l3 << 16));
        }
    }
    __syncthreads();

    const int lane = tid & 63, wave = tid >> 6;     // wave = col-tile 0..7
    const int quad = lane >> 4, col = lane & 15;
    const int nt = wave;

    // ---- 3 hidden layers: 128->128, act then re-split back into LDS ----
#pragma unroll 1
    for (int l = 0; l < 3; ++l) {
        const u16*   Whi = (l == 0) ? W0hi : (l == 1) ? W1hi : W2hi;
        const u16*   Wlo = (l == 0) ? W0lo : (l == 1) ? W1lo : W2lo;
        const float* bs  = (l == 0) ? b0   : (l == 1) ? b1   : b2;

        f32x4 acc[4];
        {
            const float bv = bs[nt * 16 + col];
#pragma unroll
            for (int m = 0; m < 4; ++m) acc[m] = (f32x4){bv, bv, bv, bv};
        }
        bf16x8 bHi[4], bLo[4];
#pragma unroll
        for (int k0 = 0; k0 < 4; ++k0) {
            const size_t off = (size_t)(nt * 16 + col) * 128 + k0 * 32 + quad * 8;
            bHi[k0] = *(const bf16x8*)(Whi + off);
            bLo[k0] = *(const bf16x8*)(Wlo + off);
        }
#pragma unroll
        for (int m = 0; m < 4; ++m) {
#pragma unroll
            for (int k0 = 0; k0 < 4; ++k0) {
                const bf16x8 aHi = *(const bf16x8*)&sHi[m * 16 + col][k0 * 32 + quad * 8];
                const bf16x8 aLo = *(const bf16x8*)&sLo[m * 16 + col][k0 * 32 + quad * 8];
                acc[m] = __builtin_amdgcn_mfma_f32_16x16x32_bf16(aHi, bHi[k0], acc[m], 0, 0, 0);
                acc[m] = __builtin_amdgcn_mfma_f32_16x16x32_bf16(aHi, bLo[k0], acc[m], 0, 0, 0);
                acc[m] = __builtin_amdgcn_mfma_f32_16x16x32_bf16(aLo, bHi[k0], acc[m], 0, 0, 0);
            }
        }
        __syncthreads();   // all waves done reading current tile

        {
            const int ct = nt * 16 + col;
#pragma unroll
            for (int m = 0; m < 4; ++m) {
#pragma unroll
                for (int r = 0; r < 4; ++r) {
                    float v = (l == 0) ? fmaxf(acc[m][r], 0.f)
                                       : fast_tanh(acc[m][r]);
                    const u16 hv = f2bf(v);
                    const u16 lv = f2bf(v - bf2f(hv));
                    const int row = m * 16 + quad * 4 + r;
                    sHi[row][ct] = hv;
                    sLo[row][ct] = lv;
                }
            }
        }
        __syncthreads();   // next-layer tile fully written
    }

    // ---- output layer: 128 -> 64, waves 0..3 (one col-tile each) ----
    if (wave < 4) {
        const float bv = b3[nt * 16 + col];
        f32x4 acc[4];
#pragma unroll
        for (int m = 0; m < 4; ++m) acc[m] = (f32x4){bv, bv, bv, bv};

        bf16x8 bHi[4], bLo[4];
#pragma unroll
        for (int k0 = 0; k0 < 4; ++k0) {
            const size_t off = (size_t)(nt * 16 + col) * 128 + k0 * 32 + quad * 8;
            bHi[k0] = *(const bf16x8*)(W3hi + off);
            bLo[k0] = *(const bf16x8*)(W3lo + off);
        }
#pragma unroll
        for (int m = 0; m < 4; ++m) {
#pragma unroll
            for (int k0 = 0; k0 < 4; ++k0) {
                const bf16x8 tHi = *(const bf16x8*)&sHi[m * 16 + col][k0 * 32 + quad * 8];
                const bf16x8 tLo = *(const bf16x8*)&sLo[m * 16 + col][k0 * 32 + quad * 8];
                acc[m] = __builtin_amdgcn_mfma_f32_16x16x32_bf16(tHi, bHi[k0], acc[m], 0, 0, 0);
                acc[m] = __builtin_amdgcn_mfma_f32_16x16x32_bf16(tHi, bLo[k0], acc[m], 0, 0, 0);
                acc[m] = __builtin_amdgcn_mfma_f32_16x16x32_bf16(tLo, bHi[k0], acc[m], 0, 0, 0);
            }
        }
#pragma unroll
        for (int m = 0; m < 4; ++m) {
#pragma unroll
            for (int r = 0; r < 4; ++r) {
                const int node = n0 + m * 16 + quad * 4 + r;
                if (node < N_NODES)
                    __builtin_nontemporal_store(acc[m][r],
                        out + (size_t)node * 64 + nt * 16 + col);
            }
        }
    }
}

// ---------------------------------------------------------------------------
extern "C" void kernel_launch(void* const* d_in, const int* in_sizes, int n_in,
                              void* d_out, int out_size, void* d_ws, size_t ws_size,
                              hipStream_t stream)
{
    const float* x   = (const float*)d_in[0];
    const int*   ei  = (const int*)  d_in[1];
    const float* ef  = (const float*)d_in[2];
    const float* We1 = (const float*)d_in[3];
    const float* be1 = (const float*)d_in[4];
    const float* W1a = (const float*)d_in[5];
    const float* b1a = (const float*)d_in[6];
    const float* W1b = (const float*)d_in[7];
    const float* b1b = (const float*)d_in[8];
    const float* We2 = (const float*)d_in[9];
    const float* be2 = (const float*)d_in[10];
    const float* W2a = (const float*)d_in[11];
    const float* b2a = (const float*)d_in[12];
    const float* W2b = (const float*)d_in[13];
    const float* b2b = (const float*)d_in[14];
    const float* Wf1 = (const float*)d_in[15];
    const float* bf1 = (const float*)d_in[16];
    const float* Wf2 = (const float*)d_in[17];
    const float* bf2 = (const float*)d_in[18];
    float* out = (float*)d_out;

    const int* src = ei;             // edge_index[0]
    const int* dst = ei + N_EDGES;   // edge_index[1]

    // ---- workspace layout ----
    float*  agg     = (float*)d_ws;                      // N*128 f
    float*  h       = agg + (size_t)N_NODES * 128;       // N*128 f
    int*    row_ptr = (int*)(h + (size_t)N_NODES * 128); // N+8 (padded)
    int*    perm    = row_ptr + (N_NODES + 8);           // E
    int*    src_s   = perm + N_EDGES;                    // E
    int*    dst_srt = src_s + N_EDGES;                   // E
    u16*    wT      = (u16*)(dst_srt + N_EDGES);         // 196608 u16 bf16 weights
    // sort temporaries overlaid on agg (dead before scatter_npre runs):
    int* counts    = (int*)agg;                          // N
    int* rank      = counts + N_NODES;                   // E
    int* blockSums = rank + N_EDGES;                     // NB_SCAN
    int* blockOffs = blockSums + NB_SCAN;                // NB_SCAN

    // transposed bf16 weight blocks (hi at +0, lo at +size)
    u16* W1aT = wT;                  // 16384 hi + 16384 lo
    u16* W1bT = wT + 32768;
    u16* W2aT = wT + 65536;
    u16* W2bT = wT + 98304;
    u16* Wf1T = wT + 131072;
    u16* Wf2T = wT + 163840;         // 8192 hi + 8192 lo
    u16* We1T = wT + 180224;         // 4096 hi + 4096 lo
    u16* We2T = wT + 188416;         // 4096 hi + 4096 lo

    const int mlpGrid = (N_NODES + 63) / 64;   // 64-row tiles, 512-thr blocks
    const int nGrid   = (N_NODES + 255) / 256;
    const int fcGrid  = N_EDGES / 64;   // 9375, exact
    const int wpGrid  = (98304 + 255) / 256;

    // NOTE: rank overlays agg rows; scatter reads rank while npre writes agg.
    // rank occupies agg[N_NODES .. N_NODES+E) ints = rows 781.. ; npre only
    // writes rows whose CSR segment is non-interior — overlap is benign
    // because scatter's rank reads complete before npre's agg writes can
    // alias them only if the same 4B words were both rank entries and
    // non-interior agg rows. To be safe, rank lives AFTER the agg+h region:
    // (see workspace layout above — rank is placed inside agg; we instead
    //  re-point rank to scratch after wT to avoid the race.)
    int* rank_safe = (int*)(wT + 196608 + 64);   // E ints, past weights

    // ---- build sorted CSR + bf16 weights (same work every call) ----
    hipMemsetAsync(counts, 0, (size_t)N_NODES * sizeof(int), stream);
    hist_wprep_k<<<EGRID + wpGrid, 256, 0, stream>>>(
        dst, counts, rank_safe, W1a, W1b, W2a, W2b, Wf1, Wf2, We1, We2, wT);
    scan_a_k <<<NB_SCAN, 256, 0, stream>>>(counts, row_ptr, blockSums);
    scan_b_k <<<1,       128, 0, stream>>>(blockSums, blockOffs);
    scan_c_k <<<nGrid,   256, 0, stream>>>(row_ptr, blockOffs);
    // scatter + conv1 npre fused (both depend only on scan_c; counts/agg
    // overlay is dead for npre rows because rank now lives in rank_safe)
    scatter_npre_k<<<EGRID + NZGRID, 256, 0, stream>>>(
        src, dst, row_ptr, rank_safe, perm, src_s, dst_srt, x, agg);

    // ---- conv1: agg = x + edge-sum, then 2-layer MLP -> h (+ agg seed) ----
    fused_conv_k<<<fcGrid, 256, 0, stream>>>(x, ef, perm, src_s, dst_srt, row_ptr,
                                             We1T, We1T + 4096, be1, agg);
    mlp2_mfma_k<<<mlpGrid, 512, 0, stream>>>(
        agg, row_ptr, W1aT, W1aT + 16384, b1a, W1bT, W1bT + 16384, b1b, h, agg);

    // ---- conv2 + head: agg = h + edge-sum, then 4-layer tail -> out ----
    fused_conv_k<<<fcGrid, 256, 0, stream>>>(h, ef, perm, src_s, dst_srt, row_ptr,
                                             We2T, We2T + 4096, be2, agg);
    mlp4_mfma_k<<<mlpGrid, 512, 0, stream>>>(
        agg,
        W2aT, W2aT + 16384, b2a,
        W2bT, W2bT + 16384, b2b,
        Wf1T, Wf1T + 16384, bf1,
        Wf2T, Wf2T + 8192,  bf2,
        out);
}

// Round 18
// 484.304 us; speedup vs baseline: 1.2423x; 1.2423x over previous
//
#include <hip/hip_runtime.h>
#include <hip/hip_fp16.h>
#include <math.h>

#define N_NODES 100000
#define N_EDGES 600000
#define NB_SCAN ((N_NODES + 1023) / 1024)   // 98 scan blocks of 1024
#define EGRID   ((N_EDGES + 255) / 256)     // 2344 edge-grid blocks
#define NZGRID  ((N_NODES * 32 + 255) / 256) // 12500 npre blocks

typedef unsigned short u16;
typedef __bf16 bf16x8 __attribute__((ext_vector_type(8)));
typedef float  f32x4  __attribute__((ext_vector_type(4)));

__device__ __forceinline__ u16 f2bf(float f) {
    union { float f; unsigned u; } c; c.f = f;
    unsigned u = c.u + 0x7fffu + ((c.u >> 16) & 1u);   // RNE
    return (u16)(u >> 16);
}
__device__ __forceinline__ float bf2f(u16 h) {
    union { unsigned u; float f; } c; c.u = ((unsigned)h) << 16;
    return c.f;
}
// fast tanh: tanh(x) = 1 - 2/(exp(2x)+1); saturates correctly at +-inf.
__device__ __forceinline__ float fast_tanh(float x) {
    float e = __expf(2.0f * x);                 // v_exp_f32 path
    return 1.0f - 2.0f * __builtin_amdgcn_rcpf(e + 1.0f);
}

// ===========================================================================
// CSR build: counting sort of edges by dst (once per launch).
// hist fused with weight prep (independent work, disjoint block ranges).
// ===========================================================================
__global__ void hist_wprep_k(const int* __restrict__ dst, int* __restrict__ counts,
                             int* __restrict__ rank,
                             const float* __restrict__ W1a, const float* __restrict__ W1b,
                             const float* __restrict__ W2a, const float* __restrict__ W2b,
                             const float* __restrict__ Wf1, const float* __restrict__ Wf2,
                             const float* __restrict__ We1, const float* __restrict__ We2,
                             u16* __restrict__ wT)
{
    if (blockIdx.x < EGRID) {               // ---- hist part ----
        int e = blockIdx.x * 256 + threadIdx.x;
        if (e < N_EDGES) rank[e] = atomicAdd(&counts[dst[e]], 1);
        return;
    }
    // ---- weight-prep part ----
    int idx = (blockIdx.x - EGRID) * 256 + threadIdx.x;
    if (idx >= 98304) return;
    if (idx >= 90112) {                    // edge-linear WeT blocks
        int l = idx - 90112;               // 0..8191
        const int m = l >> 12;             // 0: We1, 1: We2
        l &= 4095;
        const float* src = m ? We2 : We1;
        const int k = l >> 7, n = l & 127; // We is [32][128]
        const float w = src[k * 128 + n];
        const u16 hi = f2bf(w);
        const u16 lo = f2bf(w - bf2f(hi));
        const int base = 180224 + m * 8192;
        wT[base + n * 32 + k]        = hi;
        wT[base + 4096 + n * 32 + k] = lo;
        return;
    }
    int m, local;
    if      (idx < 16384) { m = 0; local = idx; }
    else if (idx < 32768) { m = 1; local = idx - 16384; }
    else if (idx < 49152) { m = 2; local = idx - 32768; }
    else if (idx < 65536) { m = 3; local = idx - 49152; }
    else if (idx < 81920) { m = 4; local = idx - 65536; }
    else                  { m = 5; local = idx - 81920; }
    const int N = (m == 5) ? 64 : 128;
    const float* src = (m == 0) ? W1a : (m == 1) ? W1b : (m == 2) ? W2a
                     : (m == 3) ? W2b : (m == 4) ? Wf1 : Wf2;
    const int k = local / N, n = local % N;
    const float w = src[k * N + n];
    const u16 hi = f2bf(w);
    const u16 lo = f2bf(w - bf2f(hi));
    const int base = m * 32768;
    const int sz   = (m == 5) ? 8192 : 16384;
    wT[base + n * 128 + k]      = hi;
    wT[base + sz + n * 128 + k] = lo;
}

__global__ void scan_a_k(const int* __restrict__ counts, int* __restrict__ row_ptr,
                         int* __restrict__ blockSums)
{
    __shared__ int s[256];
    const int t = threadIdx.x;
    const int base = blockIdx.x * 1024 + t * 4;
    int c[4];
#pragma unroll
    for (int j = 0; j < 4; ++j) c[j] = (base + j < N_NODES) ? counts[base + j] : 0;
    const int tot = c[0] + c[1] + c[2] + c[3];
    s[t] = tot;
    __syncthreads();
    for (int off = 1; off < 256; off <<= 1) {
        int v = (t >= off) ? s[t - off] : 0;
        __syncthreads();
        s[t] += v;
        __syncthreads();
    }
    int run = s[t] - tot;
#pragma unroll
    for (int j = 0; j < 4; ++j) {
        if (base + j < N_NODES) row_ptr[base + j] = run;
        run += c[j];
    }
    if (t == 255) blockSums[blockIdx.x] = s[255];
}

// Parallel 128-wide Hillis-Steele scan over the 98 block sums.
__global__ void scan_b_k(const int* __restrict__ blockSums, int* __restrict__ blockOffs)
{
    __shared__ int s[128];
    const int t = threadIdx.x;
    const int v = (t < NB_SCAN) ? blockSums[t] : 0;
    s[t] = v;
    __syncthreads();
    for (int off = 1; off < 128; off <<= 1) {
        const int u = (t >= off) ? s[t - off] : 0;
        __syncthreads();
        s[t] += u;
        __syncthreads();
    }
    if (t < NB_SCAN) blockOffs[t] = s[t] - v;   // exclusive prefix
}

__global__ void scan_c_k(int* __restrict__ row_ptr, const int* __restrict__ blockOffs)
{
    int i = blockIdx.x * 256 + threadIdx.x;
    if (i < N_NODES) row_ptr[i] += blockOffs[i >> 10];
    if (i == 0) row_ptr[N_NODES] = N_EDGES;
}

// Scatter (edge sort) fused with npre (agg[n]=x[n] preload for non-interior
// rows). Both depend only on scan_c; disjoint block ranges.
__global__ void scatter_npre_k(const int* __restrict__ src, const int* __restrict__ dst,
                               const int* __restrict__ row_ptr, const int* __restrict__ rank,
                               int* __restrict__ perm, int* __restrict__ src_sorted,
                               int* __restrict__ dst_sorted,
                               const float* __restrict__ xin, float* __restrict__ agg)
{
    if (blockIdx.x < EGRID) {               // ---- scatter part ----
        int e = blockIdx.x * 256 + threadIdx.x;
        if (e < N_EDGES) {
            int pos = row_ptr[dst[e]] + rank[e];
            perm[pos] = e;
            src_sorted[pos] = src[e];
            dst_sorted[pos] = dst[e];
        }
        return;
    }
    // ---- npre part: 32 threads per node, one float4 each ----
    const int idx = (blockIdx.x - EGRID) * 256 + threadIdx.x;
    const int n = idx >> 5;
    if (n >= N_NODES) return;
    const int rs = row_ptr[n], re = row_ptr[n + 1];
    const bool interior = (rs < re) && ((rs >> 6) == ((re - 1) >> 6));
    if (!interior) {
        const int c = (idx & 31) * 4;
        *(float4*)(agg + (size_t)n * 128 + c) =
            *(const float4*)(xin + (size_t)n * 128 + c);
    }
}

// ===========================================================================
// FUSED conv kernel — round-12 proven body + round-15 nt ef loads, at the
// PROVEN (256,6) launch bounds. (256,8) spilled (round 17: WRITE 61.7->258
// MB) because the unified VGPR+AGPR live set (~40 arch + 32 acc) exceeds
// the 64-reg cap at 8 waves/EU; reported VGPR_Count excludes accumulators.
// ===========================================================================
__global__ __launch_bounds__(256, 6) void fused_conv_k(
    const float* __restrict__ x, const float* __restrict__ ef,
    const int* __restrict__ perm, const int* __restrict__ src_s,
    const int* __restrict__ dst_s, const int* __restrict__ row_ptr,
    const u16* __restrict__ WeT_hi, const u16* __restrict__ WeT_lo,
    const float* __restrict__ be, float* __restrict__ agg)
{
    __shared__ __align__(16) char smem[16896];      // union: ef hi/lo | msg16
    u16 (*efHi)[40]  = (u16 (*)[40])smem;                    // 5120 B
    u16 (*efLo)[40]  = (u16 (*)[40])(smem + 5120);           // 5120 B
    u16 (*msg16)[132] = (u16 (*)[132])smem;                  // 16896 B overlay
    __shared__ int sSrc[64];
    __shared__ int sDst[64];

    const int t  = threadIdx.x;
    const int i0 = blockIdx.x * 64;

    // ---- stage: ef rows -> bf16 hi/lo tile; edge ids ----
    if (t < 64) { sSrc[t] = src_s[i0 + t]; sDst[t] = dst_s[i0 + t]; }
    {
        const int row = t >> 2;
        const int q   = t & 3;                      // k-range q*8 .. q*8+7
        const int e   = perm[i0 + row];
        const f32x4* p = (const f32x4*)(ef + (size_t)e * 32 + q * 8);
        const f32x4 v0 = __builtin_nontemporal_load(p);       // read-once stream
        const f32x4 v1 = __builtin_nontemporal_load(p + 1);   // -> nt hint
        const float vv[8] = {v0.x, v0.y, v0.z, v0.w, v1.x, v1.y, v1.z, v1.w};
        unsigned hp[4], lp[4];
#pragma unroll
        for (int i = 0; i < 4; ++i) {
            const u16 h0 = f2bf(vv[2 * i]),     h1 = f2bf(vv[2 * i + 1]);
            const u16 l0 = f2bf(vv[2 * i]     - bf2f(h0));
            const u16 l1 = f2bf(vv[2 * i + 1] - bf2f(h1));
            hp[i] = (unsigned)h0 | ((unsigned)h1 << 16);
            lp[i] = (unsigned)l0 | ((unsigned)l1 << 16);
        }
        *(uint4*)&efHi[row][q * 8] = make_uint4(hp[0], hp[1], hp[2], hp[3]);
        *(uint4*)&efLo[row][q * 8] = make_uint4(lp[0], lp[1], lp[2], lp[3]);
    }
    __syncthreads();

    const int lane = t & 63, wave = t >> 6;
    const int quad = lane >> 4, col = lane & 15;

    // ---- B fragments (WeT, L2-hot) for this wave's 2 col-tiles ----
    bf16x8 bHi[2], bLo[2];
#pragma unroll
    for (int j = 0; j < 2; ++j) {
        const int nt = wave * 2 + j;
        const size_t off = (size_t)(nt * 16 + col) * 32 + quad * 8;
        bHi[j] = *(const bf16x8*)(WeT_hi + off);
        bLo[j] = *(const bf16x8*)(WeT_lo + off);
    }

    // ---- x gather (32 independent dwords; latency hides under MFMA) ----
    float xv[2][4][4];
#pragma unroll
    for (int m = 0; m < 4; ++m)
#pragma unroll
        for (int r = 0; r < 4; ++r) {
            const int s = sSrc[m * 16 + quad * 4 + r];
            const float* xp = x + (size_t)s * 128 + wave * 32 + col;
            xv[0][m][r] = xp[0];
            xv[1][m][r] = xp[16];
        }

    // ---- MFMA: e = ef @ We + be (3-term hi/lo) ----
    f32x4 acc[2][4];
#pragma unroll
    for (int j = 0; j < 2; ++j) {
        const float bv = be[wave * 32 + j * 16 + col];
#pragma unroll
        for (int m = 0; m < 4; ++m) acc[j][m] = (f32x4){bv, bv, bv, bv};
    }
#pragma unroll
    for (int m = 0; m < 4; ++m) {
        const bf16x8 aHi = *(const bf16x8*)&efHi[m * 16 + col][quad * 8];
        const bf16x8 aLo = *(const bf16x8*)&efLo[m * 16 + col][quad * 8];
#pragma unroll
        for (int j = 0; j < 2; ++j) {
            acc[j][m] = __builtin_amdgcn_mfma_f32_16x16x32_bf16(aHi, bHi[j], acc[j][m], 0, 0, 0);
            acc[j][m] = __builtin_amdgcn_mfma_f32_16x16x32_bf16(aHi, bLo[j], acc[j][m], 0, 0, 0);
            acc[j][m] = __builtin_amdgcn_mfma_f32_16x16x32_bf16(aLo, bHi[j], acc[j][m], 0, 0, 0);
        }
    }

    // ---- msg = relu(x + e) in regs ----
#pragma unroll
    for (int j = 0; j < 2; ++j)
#pragma unroll
        for (int m = 0; m < 4; ++m)
#pragma unroll
            for (int r = 0; r < 4; ++r)
                acc[j][m][r] = fmaxf(acc[j][m][r] + xv[j][m][r], 0.f);

    __syncthreads();            // all ef-tile reads done -> overlay as msg16
#pragma unroll
    for (int j = 0; j < 2; ++j)
#pragma unroll
        for (int m = 0; m < 4; ++m)
#pragma unroll
            for (int r = 0; r < 4; ++r) {
                const __half hv = __float2half_rn(acc[j][m][r]);
                msg16[m * 16 + quad * 4 + r][wave * 32 + j * 16 + col] =
                    *(const u16*)&hv;
            }
    __syncthreads();

    // ---- phase 2: per-node segment sum (fp32 acc) + store/atomic ----
    const int c2 = lane * 2;
    const int nF = sDst[0], nL = sDst[63];
    for (int n = nF + wave; n <= nL; n += 4) {
        const int rs = row_ptr[n];
        const int re = row_ptr[n + 1];
        const float2 xn = *(const float2*)(x + (size_t)n * 128 + c2);  // dst row
        const int lo = rs > i0 ? rs : i0;
        const int hi = re < i0 + 64 ? re : i0 + 64;
        float a0 = 0.f, a1 = 0.f;
        for (int i = lo; i < hi; ++i) {
            const __half2 v = *(const __half2*)(&msg16[i - i0][c2]);
            const float2 f = __half22float2(v);
            a0 += f.x; a1 += f.y;
        }
        float* dp = agg + (size_t)n * 128 + c2;
        const bool interior = (rs >= i0) && (re <= i0 + 64);
        if (interior) {
            *(float2*)dp = make_float2(xn.x + a0, xn.y + a1);
        } else if (hi > lo) {
            atomicAdd(dp,     a0);
            atomicAdd(dp + 1, a1);
        }
    }
}

// ===========================================================================
// Fused 2-layer node MLP (conv1), round-12 proven: 64-row tile, 512 thr /
// 8 waves, ONE col-tile per wave, (512,4). Also seeds agg for conv2's
// non-interior rows (npre fold).
// ===========================================================================
__global__ __launch_bounds__(512, 4) void mlp2_mfma_k(
    const float* __restrict__ agg_in, const int* __restrict__ row_ptr,
    const u16* __restrict__ WaT_hi, const u16* __restrict__ WaT_lo,
    const float* __restrict__ ba,
    const u16* __restrict__ WbT_hi, const u16* __restrict__ WbT_lo,
    const float* __restrict__ bb,
    float* __restrict__ h_out, float* __restrict__ agg_out)
{
    __shared__ u16 sHi[64][136];
    __shared__ u16 sLo[64][136];
    __shared__ int sFlag[64];          // 1 = interior (skip agg preload write)
    const int tid = threadIdx.x;
    const int n0  = blockIdx.x * 64;

    // ---- stage tile: fp32 agg -> bf16 hi/lo in LDS; interior flags ----
    if (tid < 64) {
        int flag = 1;
        const int node = n0 + tid;
        if (node < N_NODES) {
            const int rs = row_ptr[node], re = row_ptr[node + 1];
            flag = (rs < re) && ((rs >> 6) == ((re - 1) >> 6));
        }
        sFlag[tid] = flag;
    }
    {
        const int mrow = tid >> 5, kq = tid & 31;   // mrow 0..15
#pragma unroll
        for (int g = 0; g < 4; ++g) {
            const int row  = g * 16 + mrow;
            const int node = n0 + row;
            float4 v = make_float4(0.f, 0.f, 0.f, 0.f);
            if (node < N_NODES)
                v = *(const float4*)(agg_in + (size_t)node * 128 + kq * 4);
            const u16 h0 = f2bf(v.x), h1 = f2bf(v.y), h2 = f2bf(v.z), h3 = f2bf(v.w);
            const u16 l0 = f2bf(v.x - bf2f(h0)), l1 = f2bf(v.y - bf2f(h1));
            const u16 l2 = f2bf(v.z - bf2f(h2)), l3 = f2bf(v.w - bf2f(h3));
            *(uint2*)&sHi[row][kq * 4] =
                make_uint2((unsigned)h0 | ((unsigned)h1 << 16), (unsigned)h2 | ((unsigned)h3 << 16));
            *(uint2*)&sLo[row][kq * 4] =
                make_uint2((unsigned)l0 | ((unsigned)l1 << 16), (unsigned)l2 | ((unsigned)l3 << 16));
        }
    }
    __syncthreads();

    const int lane = tid & 63, wave = tid >> 6;     // wave = col-tile 0..7
    const int quad = lane >> 4, col = lane & 15;
    const int nt = wave;

    // ---- layer A: this wave's col-tile across all 64 rows ----
    f32x4 accA[4];
    {
        const float bv = ba[nt * 16 + col];
#pragma unroll
        for (int m = 0; m < 4; ++m) accA[m] = (f32x4){bv, bv, bv, bv};
    }
    {
        bf16x8 bHi[4], bLo[4];
#pragma unroll
        for (int k0 = 0; k0 < 4; ++k0) {
            const size_t off = (size_t)(nt * 16 + col) * 128 + k0 * 32 + quad * 8;
            bHi[k0] = *(const bf16x8*)(WaT_hi + off);
            bLo[k0] = *(const bf16x8*)(WaT_lo + off);
        }
#pragma unroll
        for (int m = 0; m < 4; ++m) {
#pragma unroll
            for (int k0 = 0; k0 < 4; ++k0) {
                const bf16x8 aHi = *(const bf16x8*)&sHi[m * 16 + col][k0 * 32 + quad * 8];
                const bf16x8 aLo = *(const bf16x8*)&sLo[m * 16 + col][k0 * 32 + quad * 8];
                accA[m] = __builtin_amdgcn_mfma_f32_16x16x32_bf16(aHi, bHi[k0], accA[m], 0, 0, 0);
                accA[m] = __builtin_amdgcn_mfma_f32_16x16x32_bf16(aHi, bLo[k0], accA[m], 0, 0, 0);
                accA[m] = __builtin_amdgcn_mfma_f32_16x16x32_bf16(aLo, bHi[k0], accA[m], 0, 0, 0);
            }
        }
    }
    __syncthreads();   // all waves done READING the input tile

    // ---- relu + re-split t into the same LDS buffer ----
    {
        const int ct = nt * 16 + col;
#pragma unroll
        for (int m = 0; m < 4; ++m) {
#pragma unroll
            for (int r = 0; r < 4; ++r) {
                float v = fmaxf(accA[m][r], 0.f);
                const u16 hv = f2bf(v);
                const u16 lv = f2bf(v - bf2f(hv));
                const int row = m * 16 + quad * 4 + r;
                sHi[row][ct] = hv;
                sLo[row][ct] = lv;
            }
        }
    }
    __syncthreads();   // t tile fully written

    // ---- layer B: out = tanh(t @ Wb + bb); also seed agg for conv2 ----
    {
        const float bv = bb[nt * 16 + col];
        f32x4 accB[4];
#pragma unroll
        for (int m = 0; m < 4; ++m) accB[m] = (f32x4){bv, bv, bv, bv};

        bf16x8 bHi[4], bLo[4];
#pragma unroll
        for (int k0 = 0; k0 < 4; ++k0) {
            const size_t off = (size_t)(nt * 16 + col) * 128 + k0 * 32 + quad * 8;
            bHi[k0] = *(const bf16x8*)(WbT_hi + off);
            bLo[k0] = *(const bf16x8*)(WbT_lo + off);
        }
#pragma unroll
        for (int m = 0; m < 4; ++m) {
#pragma unroll
            for (int k0 = 0; k0 < 4; ++k0) {
                const bf16x8 tHi = *(const bf16x8*)&sHi[m * 16 + col][k0 * 32 + quad * 8];
                const bf16x8 tLo = *(const bf16x8*)&sLo[m * 16 + col][k0 * 32 + quad * 8];
                accB[m] = __builtin_amdgcn_mfma_f32_16x16x32_bf16(tHi, bHi[k0], accB[m], 0, 0, 0);
                accB[m] = __builtin_amdgcn_mfma_f32_16x16x32_bf16(tHi, bLo[k0], accB[m], 0, 0, 0);
                accB[m] = __builtin_amdgcn_mfma_f32_16x16x32_bf16(tLo, bHi[k0], accB[m], 0, 0, 0);
            }
        }
#pragma unroll
        for (int m = 0; m < 4; ++m) {
#pragma unroll
            for (int r = 0; r < 4; ++r) {
                const int row  = m * 16 + quad * 4 + r;
                const int node = n0 + row;
                if (node < N_NODES) {
                    const float v = fast_tanh(accB[m][r]);
                    const size_t o = (size_t)node * 128 + nt * 16 + col;
                    h_out[o] = v;
                    if (!sFlag[row]) agg_out[o] = v;   // conv2 npre fold
                }
            }
        }
    }
}

// ===========================================================================
// Fused 4-layer tail (conv2 MLP + head), round-12 proven: 64-row tile,
// 512 thr / 8 waves, one col-tile per wave; final layer uses waves 0..3.
// out store is NON-TEMPORAL (never re-read; keeps h/agg cache-resident).
// ===========================================================================
__global__ __launch_bounds__(512, 4) void mlp4_mfma_k(
    const float* __restrict__ agg,
    const u16* __restrict__ W0hi, const u16* __restrict__ W0lo, const float* __restrict__ b0,
    const u16* __restrict__ W1hi, const u16* __restrict__ W1lo, const float* __restrict__ b1,
    const u16* __restrict__ W2hi, const u16* __restrict__ W2lo, const float* __restrict__ b2,
    const u16* __restrict__ W3hi, const u16* __restrict__ W3lo, const float* __restrict__ b3,
    float* __restrict__ out)
{
    __shared__ u16 sHi[64][136];
    __shared__ u16 sLo[64][136];
    const int tid = threadIdx.x;
    const int n0  = blockIdx.x * 64;

    // ---- stage tile: fp32 agg -> bf16 hi/lo in LDS ----
    {
        const int mrow = tid >> 5, kq = tid & 31;   // mrow 0..15
#pragma unroll
        for (int g = 0; g < 4; ++g) {
            const int row  = g * 16 + mrow;
            const int node = n0 + row;
            float4 v = make_float4(0.f, 0.f, 0.f, 0.f);
            if (node < N_NODES)
                v = *(const float4*)(agg + (size_t)node * 128 + kq * 4);
            const u16 h0 = f2bf(v.x), h1 = f2bf(v.y), h2 = f2bf(v.z), h3 = f2bf(v.w);
            const u16 l0 = f2bf(v.x - bf2f(h0)), l1 = f2bf(v.y - bf2f(h1));
            const u16 l2 = f2bf(v.z - bf2f(h2)), l3 = f2bf(v.w - bf2f(h3));
            *(uint2*)&sHi[row][kq * 4] =
                make_uint2((unsigned)h0 | ((unsigned)h1 << 16), (unsigned)h2 | ((unsigned)h3 << 16));
            *(uint2*)&sLo[row][kq * 4] =
                make_uint2((unsigned)l0 | ((unsigned)l1 << 16), (unsigned)l2 | ((unsigned)l3 << 16));
        }
    }
    __syncthreads();

    const int lane = tid & 63, wave = tid >> 6;     // wave = col-tile 0..7
    const int quad = lane >> 4, col = lane & 15;
    const int nt = wave;

    // ---- 3 hidden layers: 128->128, act then re-split back into LDS ----
#pragma unroll 1
    for (int l = 0; l < 3; ++l) {
        const u16*   Whi = (l == 0) ? W0hi : (l == 1) ? W1hi : W2hi;
        const u16*   Wlo = (l == 0) ? W0lo : (l == 1) ? W1lo : W2lo;
        const float* bs  = (l == 0) ? b0   : (l == 1) ? b1   : b2;

        f32x4 acc[4];
        {
            const float bv = bs[nt * 16 + col];
#pragma unroll
            for (int m = 0; m < 4; ++m) acc[m] = (f32x4){bv, bv, bv, bv};
        }
        bf16x8 bHi[4], bLo[4];
#pragma unroll
        for (int k0 = 0; k0 < 4; ++k0) {
            const size_t off = (size_t)(nt * 16 + col) * 128 + k0 * 32 + quad * 8;
            bHi[k0] = *(const bf16x8*)(Whi + off);
            bLo[k0] = *(const bf16x8*)(Wlo + off);
        }
#pragma unroll
        for (int m = 0; m < 4; ++m) {
#pragma unroll
            for (int k0 = 0; k0 < 4; ++k0) {
                const bf16x8 aHi = *(const bf16x8*)&sHi[m * 16 + col][k0 * 32 + quad * 8];
                const bf16x8 aLo = *(const bf16x8*)&sLo[m * 16 + col][k0 * 32 + quad * 8];
                acc[m] = __builtin_amdgcn_mfma_f32_16x16x32_bf16(aHi, bHi[k0], acc[m], 0, 0, 0);
                acc[m] = __builtin_amdgcn_mfma_f32_16x16x32_bf16(aHi, bLo[k0], acc[m], 0, 0, 0);
                acc[m] = __builtin_amdgcn_mfma_f32_16x16x32_bf16(aLo, bHi[k0], acc[m], 0, 0, 0);
            }
        }
        __syncthreads();   // all waves done reading current tile

        {
            const int ct = nt * 16 + col;
#pragma unroll
            for (int m = 0; m < 4; ++m) {
#pragma unroll
                for (int r = 0; r < 4; ++r) {
                    float v = (l == 0) ? fmaxf(acc[m][r], 0.f)
                                       : fast_tanh(acc[m][r]);
                    const u16 hv = f2bf(v);
                    const u16 lv = f2bf(v - bf2f(hv));
                    const int row = m * 16 + quad * 4 + r;
                    sHi[row][ct] = hv;
                    sLo[row][ct] = lv;
                }
            }
        }
        __syncthreads();   // next-layer tile fully written
    }

    // ---- output layer: 128 -> 64, waves 0..3 (one col-tile each) ----
    if (wave < 4) {
        const float bv = b3[nt * 16 + col];
        f32x4 acc[4];
#pragma unroll
        for (int m = 0; m < 4; ++m) acc[m] = (f32x4){bv, bv, bv, bv};

        bf16x8 bHi[4], bLo[4];
#pragma unroll
        for (int k0 = 0; k0 < 4; ++k0) {
            const size_t off = (size_t)(nt * 16 + col) * 128 + k0 * 32 + quad * 8;
            bHi[k0] = *(const bf16x8*)(W3hi + off);
            bLo[k0] = *(const bf16x8*)(W3lo + off);
        }
#pragma unroll
        for (int m = 0; m < 4; ++m) {
#pragma unroll
            for (int k0 = 0; k0 < 4; ++k0) {
                const bf16x8 tHi = *(const bf16x8*)&sHi[m * 16 + col][k0 * 32 + quad * 8];
                const bf16x8 tLo = *(const bf16x8*)&sLo[m * 16 + col][k0 * 32 + quad * 8];
                acc[m] = __builtin_amdgcn_mfma_f32_16x16x32_bf16(tHi, bHi[k0], acc[m], 0, 0, 0);
                acc[m] = __builtin_amdgcn_mfma_f32_16x16x32_bf16(tHi, bLo[k0], acc[m], 0, 0, 0);
                acc[m] = __builtin_amdgcn_mfma_f32_16x16x32_bf16(tLo, bHi[k0], acc[m], 0, 0, 0);
            }
        }
#pragma unroll
        for (int m = 0; m < 4; ++m) {
#pragma unroll
            for (int r = 0; r < 4; ++r) {
                const int node = n0 + m * 16 + quad * 4 + r;
                if (node < N_NODES)
                    __builtin_nontemporal_store(acc[m][r],
                        out + (size_t)node * 64 + nt * 16 + col);
            }
        }
    }
}

// ---------------------------------------------------------------------------
extern "C" void kernel_launch(void* const* d_in, const int* in_sizes, int n_in,
                              void* d_out, int out_size, void* d_ws, size_t ws_size,
                              hipStream_t stream)
{
    const float* x   = (const float*)d_in[0];
    const int*   ei  = (const int*)  d_in[1];
    const float* ef  = (const float*)d_in[2];
    const float* We1 = (const float*)d_in[3];
    const float* be1 = (const float*)d_in[4];
    const float* W1a = (const float*)d_in[5];
    const float* b1a = (const float*)d_in[6];
    const float* W1b = (const float*)d_in[7];
    const float* b1b = (const float*)d_in[8];
    const float* We2 = (const float*)d_in[9];
    const float* be2 = (const float*)d_in[10];
    const float* W2a = (const float*)d_in[11];
    const float* b2a = (const float*)d_in[12];
    const float* W2b = (const float*)d_in[13];
    const float* b2b = (const float*)d_in[14];
    const float* Wf1 = (const float*)d_in[15];
    const float* bf1 = (const float*)d_in[16];
    const float* Wf2 = (const float*)d_in[17];
    const float* bf2 = (const float*)d_in[18];
    float* out = (float*)d_out;

    const int* src = ei;             // edge_index[0]
    const int* dst = ei + N_EDGES;   // edge_index[1]

    // ---- workspace layout ----
    float*  agg     = (float*)d_ws;                      // N*128 f
    float*  h       = agg + (size_t)N_NODES * 128;       // N*128 f
    int*    row_ptr = (int*)(h + (size_t)N_NODES * 128); // N+8 (padded)
    int*    perm    = row_ptr + (N_NODES + 8);           // E
    int*    src_s   = perm + N_EDGES;                    // E
    int*    dst_srt = src_s + N_EDGES;                   // E
    u16*    wT      = (u16*)(dst_srt + N_EDGES);         // 196608 u16 bf16 weights
    // sort temporaries overlaid on agg (dead before scatter_npre runs):
    int* counts    = (int*)agg;                          // N
    int* blockSums = counts + N_NODES;                   // NB_SCAN
    int* blockOffs = blockSums + NB_SCAN;                // NB_SCAN
    // rank lives past the weight blocks (NOT overlaid on agg, since the
    // fused scatter_npre kernel reads rank while writing agg)
    int* rank_safe = (int*)(wT + 196608 + 64);           // E ints

    // transposed bf16 weight blocks (hi at +0, lo at +size)
    u16* W1aT = wT;                  // 16384 hi + 16384 lo
    u16* W1bT = wT + 32768;
    u16* W2aT = wT + 65536;
    u16* W2bT = wT + 98304;
    u16* Wf1T = wT + 131072;
    u16* Wf2T = wT + 163840;         // 8192 hi + 8192 lo
    u16* We1T = wT + 180224;         // 4096 hi + 4096 lo
    u16* We2T = wT + 188416;         // 4096 hi + 4096 lo

    const int mlpGrid = (N_NODES + 63) / 64;   // 64-row tiles, 512-thr blocks
    const int nGrid   = (N_NODES + 255) / 256;
    const int fcGrid  = N_EDGES / 64;   // 9375, exact
    const int wpGrid  = (98304 + 255) / 256;

    // ---- build sorted CSR + bf16 weights (same work every call) ----
    hipMemsetAsync(counts, 0, (size_t)N_NODES * sizeof(int), stream);
    hist_wprep_k<<<EGRID + wpGrid, 256, 0, stream>>>(
        dst, counts, rank_safe, W1a, W1b, W2a, W2b, Wf1, Wf2, We1, We2, wT);
    scan_a_k <<<NB_SCAN, 256, 0, stream>>>(counts, row_ptr, blockSums);
    scan_b_k <<<1,       128, 0, stream>>>(blockSums, blockOffs);
    scan_c_k <<<nGrid,   256, 0, stream>>>(row_ptr, blockOffs);
    // scatter + conv1 npre fused (both depend only on scan_c)
    scatter_npre_k<<<EGRID + NZGRID, 256, 0, stream>>>(
        src, dst, row_ptr, rank_safe, perm, src_s, dst_srt, x, agg);

    // ---- conv1: agg = x + edge-sum, then 2-layer MLP -> h (+ agg seed) ----
    fused_conv_k<<<fcGrid, 256, 0, stream>>>(x, ef, perm, src_s, dst_srt, row_ptr,
                                             We1T, We1T + 4096, be1, agg);
    mlp2_mfma_k<<<mlpGrid, 512, 0, stream>>>(
        agg, row_ptr, W1aT, W1aT + 16384, b1a, W1bT, W1bT + 16384, b1b, h, agg);

    // ---- conv2 + head: agg = h + edge-sum, then 4-layer tail -> out ----
    fused_conv_k<<<fcGrid, 256, 0, stream>>>(h, ef, perm, src_s, dst_srt, row_ptr,
                                             We2T, We2T + 4096, be2, agg);
    mlp4_mfma_k<<<mlpGrid, 512, 0, stream>>>(
        agg,
        W2aT, W2aT + 16384, b2a,
        W2bT, W2bT + 16384, b2b,
        Wf1T, Wf1T + 16384, bf1,
        Wf2T, Wf2T + 8192,  bf2,
        out);
}